// Round 5
// baseline (85.941 us; speedup 1.0000x reference)
//
#include <hip/hip_runtime.h>
#include <hip/hip_bf16.h>
#include <cstdint>
#include <cstddef>

#define TOKENS 16384
#define DMODEL 4096
#define NEXP   64
#define NWIN   16
#define WINK   256                    // k-floats per window (8 chunks of 32)
#define NKC2   128                    // total K=32 chunks

typedef __attribute__((ext_vector_type(8))) short bf16x8;   // 8 bf16 = 4 VGPRs
typedef __attribute__((ext_vector_type(4))) float f32x4;    // 16x16 acc

// 8 fp32 -> hi/lo bf16 (RNE hi, exact residual -> lo; ~2^-17 rel)
__device__ __forceinline__ void cvt_hilo8(const float f[8], bf16x8* hi, bf16x8* lo) {
  union { __hip_bfloat16 b; unsigned short u; } cv;
  bf16x8 hv, lv;
#pragma unroll
  for (int j = 0; j < 8; ++j) {
    __hip_bfloat16 hb = __float2bfloat16(f[j]);
    cv.b = hb; hv[j] = (short)cv.u;
    float r = f[j] - __bfloat162float(hb);
    cv.b = __float2bfloat16(r); lv[j] = (short)cv.u;
  }
  *hi = hv; *lo = lv;
}

// ---------------- kernel 1: W -> 16x16x32 B-fragments, bf16 hi/lo ----------------
// slot (kc2*4+eg)*64+l <- B[k=kc2*32+(l>>4)*8+j][e=eg*16+(l&15)] = W[e][k+j]
__global__ __launch_bounds__(256)
void prep_W(const float* __restrict__ W, uint4* __restrict__ wh, uint4* __restrict__ wl) {
  const int tid = blockIdx.x * 256 + threadIdx.x;   // 32768 threads
  const int l   = tid & 63;
  const int eg  = (tid >> 6) & 3;
  const int kc2 = tid >> 8;                          // 0..127
  const int e   = eg * 16 + (l & 15);
  const int k   = kc2 * 32 + (l >> 4) * 8;
  const float* src = W + (size_t)e * DMODEL + k;
  float f[8];
#pragma unroll
  for (int j = 0; j < 8; ++j) f[j] = src[j];
  bf16x8 hi, lo;
  cvt_hilo8(f, &hi, &lo);
  const int slot = (kc2 * 4 + eg) * 64 + l;
  wh[slot] = __builtin_bit_cast(uint4, hi);
  wl[slot] = __builtin_bit_cast(uint4, lo);
}

// swizzled LDS byte address for fragment slot s = (kc2l*2+mt)*64+lane
__device__ __forceinline__ int xaddr(int s) {
  return (s * 16) ^ (((s >> 7) & 7) << 4);
}

// global->reg: 8 float4, 1KB-contiguous runs per row (2 rows/instr-pair)
__device__ __forceinline__ void loadx4(const float* __restrict__ x, int t0, int w, int l,
                                       int win, float4 L[8]) {
#pragma unroll
  for (int j = 0; j < 4; ++j) {
    const float* p = x + (size_t)(t0 + w * 8 + 2 * j + (l >> 5)) * DMODEL
                       + win * WINK + (l & 31) * 8;
    L[j * 2]     = *(const float4*)p;
    L[j * 2 + 1] = *(const float4*)(p + 4);
  }
}

// reg -> cvt -> swizzled LDS fragment store (conflict-free by construction)
__device__ __forceinline__ void cvtwrite(char* hb, char* lb, int w, int l,
                                         const float4 L[8]) {
  const int kc2l = (l & 31) >> 2;
  const int ksub = l & 3;
  const int mt   = w >> 1;
#pragma unroll
  for (int j = 0; j < 4; ++j) {
    const int r  = w * 8 + 2 * j + (l >> 5);
    const int lp = (r & 15) + ksub * 16;
    const int a  = xaddr((kc2l * 2 + mt) * 64 + lp);
    float f[8] = {L[j*2].x, L[j*2].y, L[j*2].z, L[j*2].w,
                  L[j*2+1].x, L[j*2+1].y, L[j*2+1].z, L[j*2+1].w};
    bf16x8 hi, lo;
    cvt_hilo8(f, &hi, &lo);
    *(bf16x8*)(hb + a) = hi;
    *(bf16x8*)(lb + a) = lo;
  }
}

__device__ __forceinline__ void compute_win(const char* hb, const char* lb, int wi, int l,
    const uint4* __restrict__ whp, const uint4* __restrict__ wlp,
    uint4 (&ph)[2], uint4 (&pl)[2], f32x4& acc0, f32x4& acc1) {
#pragma unroll
  for (int c = 0; c < 8; ++c) {
    uint4 bhu = ph[c & 1], blu = pl[c & 1];
    const int kci = wi * 8 + c;
    if (kci + 2 < NKC2) {                     // depth-2 L2 rotation
      ph[c & 1] = whp[(kci + 2) * 256];
      pl[c & 1] = wlp[(kci + 2) * 256];
    }
    const int s0 = (c * 2 + 0) * 64 + l;
    const int s1 = (c * 2 + 1) * 64 + l;
    bf16x8 ah0 = *(const bf16x8*)(hb + xaddr(s0));
    bf16x8 ah1 = *(const bf16x8*)(hb + xaddr(s1));
    bf16x8 al0 = *(const bf16x8*)(lb + xaddr(s0));
    bf16x8 al1 = *(const bf16x8*)(lb + xaddr(s1));
    bf16x8 bh = __builtin_bit_cast(bf16x8, bhu);
    bf16x8 bl = __builtin_bit_cast(bf16x8, blu);
    acc0 = __builtin_amdgcn_mfma_f32_16x16x32_bf16(ah0, bh, acc0, 0, 0, 0);
    acc1 = __builtin_amdgcn_mfma_f32_16x16x32_bf16(ah1, bh, acc1, 0, 0, 0);
    acc0 = __builtin_amdgcn_mfma_f32_16x16x32_bf16(ah0, bl, acc0, 0, 0, 0);
    acc1 = __builtin_amdgcn_mfma_f32_16x16x32_bf16(ah1, bl, acc1, 0, 0, 0);
    acc0 = __builtin_amdgcn_mfma_f32_16x16x32_bf16(al0, bh, acc0, 0, 0, 0);
    acc1 = __builtin_amdgcn_mfma_f32_16x16x32_bf16(al1, bh, acc1, 0, 0, 0);
  }
}

// ---------------- kernel 2: fused GEMM (expert-split waves) + bias + top-2 + softmax ----
// 512 blocks x 256 thr (2/CU). Block = 32 tokens x 64 experts; wave w = experts [w*16,+16), full K.
__global__ __launch_bounds__(256, 2)
void gemm_topk(const float* __restrict__ x, const uint4* __restrict__ whB,
               const uint4* __restrict__ wlB, const float* __restrict__ b,
               float* __restrict__ out) {
  __shared__ __align__(16) char lds[65536];   // [buf0: hi 16K | lo 16K][buf1: hi | lo]
  const int tid = threadIdx.x;
  const int l   = tid & 63;
  const int w   = tid >> 6;
  const int t0  = blockIdx.x * 32;

  char* h0 = lds;              char* l0 = lds + 16384;
  char* h1 = lds + 32768;      char* l1 = lds + 49152;
  const uint4* whp = whB + w * 64 + l;
  const uint4* wlp = wlB + w * 64 + l;

  f32x4 acc0 = {0.f, 0.f, 0.f, 0.f}, acc1 = {0.f, 0.f, 0.f, 0.f};
  float4 LR0[8], LR1[8];

  // prologue: stage win0 -> buf0; win1 loads in flight
  loadx4(x, t0, w, l, 0, LR0);
  cvtwrite(h0, l0, w, l, LR0);
  loadx4(x, t0, w, l, 1, LR1);
  uint4 ph[2], pl[2];
  ph[0] = whp[0];   pl[0] = wlp[0];
  ph[1] = whp[256]; pl[1] = wlp[256];
  __syncthreads();

  for (int wi = 0; wi < NWIN; wi += 2) {
    if (wi + 2 < NWIN) loadx4(x, t0, w, l, wi + 2, LR0);
    cvtwrite(h1, l1, w, l, LR1);                        // win wi+1 -> buf1
    compute_win(h0, l0, wi, l, whp, wlp, ph, pl, acc0, acc1);
    __syncthreads();
    if (wi + 3 < NWIN) loadx4(x, t0, w, l, wi + 3, LR1);
    if (wi + 2 < NWIN) cvtwrite(h0, l0, w, l, LR0);     // win wi+2 -> buf0
    compute_win(h1, l1, wi + 1, l, whp, wlp, ph, pl, acc0, acc1);
    __syncthreads();
  }

  // logits -> LDS (alias buf0; safe: loop ends with barrier), + bias
  // C/D 16x16x32 (m89): col=lane&15 (expert), row=(lane>>4)*4+reg (token)
  float* red = (float*)lds;                   // [32][66]
  const float bias = b[w * 16 + (l & 15)];
#pragma unroll
  for (int reg = 0; reg < 4; ++reg) {
    const int tr = (l >> 4) * 4 + reg;
    red[tr * 66 + w * 16 + (l & 15)]        = acc0[reg] + bias;
    red[(16 + tr) * 66 + w * 16 + (l & 15)] = acc1[reg] + bias;
  }
  __syncthreads();

  // top-2 + softmax: wave w handles tokens w*8..w*8+7, lane = expert
#pragma unroll
  for (int i = 0; i < 8; ++i) {
    const int tl = w * 8 + i;
    const float v = red[tl * 66 + l];

    float m1 = v; int i1 = l;
#pragma unroll
    for (int off = 32; off > 0; off >>= 1) {
      float ov = __shfl_xor(m1, off, 64);
      int   oi = __shfl_xor(i1, off, 64);
      if (ov > m1 || (ov == m1 && oi < i1)) { m1 = ov; i1 = oi; }
    }
    float v2 = (l == i1) ? -__builtin_inff() : v;
    float m2 = v2; int i2 = l;
#pragma unroll
    for (int off = 32; off > 0; off >>= 1) {
      float ov = __shfl_xor(m2, off, 64);
      int   oi = __shfl_xor(i2, off, 64);
      if (ov > m2 || (ov == m2 && oi < i2)) { m2 = ov; i2 = oi; }
    }
    float e = __expf(v - m1);
#pragma unroll
    for (int off = 32; off > 0; off >>= 1) e += __shfl_xor(e, off, 64);

    if (l == 0) {
      const int t = t0 + tl;
      out[(size_t)t * 2 + 0] = (float)i1;
      out[(size_t)t * 2 + 1] = (float)i2;
      float inv = 1.0f / e;
      out[(size_t)TOKENS * 2 + (size_t)t * 2 + 0] = inv;
      out[(size_t)TOKENS * 2 + (size_t)t * 2 + 1] = __expf(m2 - m1) * inv;
    }
  }
}

extern "C" void kernel_launch(void* const* d_in, const int* in_sizes, int n_in,
                              void* d_out, int out_size, void* d_ws, size_t ws_size,
                              hipStream_t stream) {
  const float* x = (const float*)d_in[0];
  const float* W = (const float*)d_in[1];
  const float* b = (const float*)d_in[2];
  float* out = (float*)d_out;

  uint4* wh = (uint4*)d_ws;          // 32768 slots * 16B = 512 KB
  uint4* wl = wh + 32768;            // 512 KB

  hipLaunchKernelGGL(prep_W,    dim3(128),         dim3(256), 0, stream, W, wh, wl);
  hipLaunchKernelGGL(gemm_topk, dim3(TOKENS / 32), dim3(256), 0, stream, x, wh, wl, b, out);
}